// Round 1
// baseline (472.693 us; speedup 1.0000x reference)
//
#include <hip/hip_runtime.h>

#define NODELEN 10
#define DEG 32
#define H1PITCH 12   // h1 rows padded 10 -> 12 floats so rows are 48B, 16B-aligned

// ---------------------------------------------------------------------------
// Kernel 1: hop-1 mean aggregation.
// h1[i] = mean_j features[adj[i][j]], then h1[i][0] = 0.
// One thread per node. adj row read as 8x int4 (contiguous 128B per thread).
// Feature rows are 40B (8B aligned) -> 5x float2 gathers per neighbor.
// Output written padded to 12 floats (48B) so kernel 2 can gather with float4.
// ---------------------------------------------------------------------------
__global__ __launch_bounds__(256) void hop1_kernel(
    const float* __restrict__ features,
    const int*   __restrict__ adj,
    float*       __restrict__ h1pad,
    int N)
{
    int i = blockIdx.x * blockDim.x + threadIdx.x;
    if (i >= N) return;

    const int4* arow = (const int4*)(adj + (size_t)i * DEG);

    float s[NODELEN];
#pragma unroll
    for (int k = 0; k < NODELEN; ++k) s[k] = 0.0f;

#pragma unroll
    for (int j = 0; j < DEG / 4; ++j) {
        int4 nb = arow[j];
        int idxs[4] = {nb.x, nb.y, nb.z, nb.w};
#pragma unroll
        for (int t = 0; t < 4; ++t) {
            const float2* r = (const float2*)(features + (size_t)idxs[t] * NODELEN);
            float2 a0 = r[0], a1 = r[1], a2 = r[2], a3 = r[3], a4 = r[4];
            s[0] += a0.x; s[1] += a0.y;
            s[2] += a1.x; s[3] += a1.y;
            s[4] += a2.x; s[5] += a2.y;
            s[6] += a3.x; s[7] += a3.y;
            s[8] += a4.x; s[9] += a4.y;
        }
    }

    const float inv = 1.0f / (float)DEG;
    float4* orow = (float4*)(h1pad + (size_t)i * H1PITCH);
    float4 o0 = make_float4(0.0f,        s[1] * inv, s[2] * inv, s[3] * inv); // col0 zeroed
    float4 o1 = make_float4(s[4] * inv,  s[5] * inv, s[6] * inv, s[7] * inv);
    float4 o2 = make_float4(s[8] * inv,  s[9] * inv, 0.0f,       0.0f);      // pad
    orow[0] = o0; orow[1] = o1; orow[2] = o2;
}

// ---------------------------------------------------------------------------
// Kernel 2: hop-2 mean aggregation + emb build + full autoencoder MLP + stores.
// One thread per node. Weights are wave-uniform -> compiler emits s_load;
// 1000 unrolled FMAs per thread (trivial vs. gather cost).
// ---------------------------------------------------------------------------
__global__ __launch_bounds__(256) void hop2_mlp_kernel(
    const float* __restrict__ features,
    const int*   __restrict__ adj,
    const float* __restrict__ h1pad,
    const float* __restrict__ We1, const float* __restrict__ be1,
    const float* __restrict__ We2, const float* __restrict__ be2,
    const float* __restrict__ We3, const float* __restrict__ be3,
    const float* __restrict__ Wd1, const float* __restrict__ bd1,
    const float* __restrict__ Wd2, const float* __restrict__ bd2,
    const float* __restrict__ Wd3, const float* __restrict__ bd3,
    float* __restrict__ out_enc,   // [N][5]
    float* __restrict__ out_dec,   // [N][20]
    float* __restrict__ out_emb,   // [N][20]
    int N)
{
    int i = blockIdx.x * blockDim.x + threadIdx.x;
    if (i >= N) return;

    const int4* arow = (const int4*)(adj + (size_t)i * DEG);

    // hop-2 gather: sum of padded h1 rows, 3x float4 per neighbor
    float s0x=0.f,s0y=0.f,s0z=0.f,s0w=0.f;
    float s1x=0.f,s1y=0.f,s1z=0.f,s1w=0.f;
    float s2x=0.f,s2y=0.f;
#pragma unroll
    for (int j = 0; j < DEG / 4; ++j) {
        int4 nb = arow[j];
        int idxs[4] = {nb.x, nb.y, nb.z, nb.w};
#pragma unroll
        for (int t = 0; t < 4; ++t) {
            const float4* r = (const float4*)(h1pad + (size_t)idxs[t] * H1PITCH);
            float4 r0 = r[0], r1 = r[1], r2 = r[2];
            s0x += r0.x; s0y += r0.y; s0z += r0.z; s0w += r0.w;
            s1x += r1.x; s1y += r1.y; s1z += r1.z; s1w += r1.w;
            s2x += r2.x; s2y += r2.y;
        }
    }

    const float inv = 1.0f / (float)DEG;
    float agg[NODELEN];
    agg[0] = 0.0f;            // h1 col0 is zero, and reference re-zeroes anyway
    agg[1] = s0y * inv; agg[2] = s0z * inv; agg[3] = s0w * inv;
    agg[4] = s1x * inv; agg[5] = s1y * inv; agg[6] = s1z * inv; agg[7] = s1w * inv;
    agg[8] = s2x * inv; agg[9] = s2y * inv;

    // self features (raw row, 5x float2)
    const float2* fr = (const float2*)(features + (size_t)i * NODELEN);
    float2 f0 = fr[0], f1 = fr[1], f2 = fr[2], f3 = fr[3], f4 = fr[4];

    float emb[2 * NODELEN];
    emb[0] = 0.0f;  emb[1] = f0.y;
    emb[2] = f1.x;  emb[3] = f1.y;
    emb[4] = f2.x;  emb[5] = f2.y;
    emb[6] = f3.x;  emb[7] = f3.y;
    emb[8] = f4.x;  emb[9] = f4.y;
    emb[10] = 0.0f;
#pragma unroll
    for (int k = 1; k < NODELEN; ++k) emb[10 + k] = agg[k];

    // ---- autoencoder (all loops fully unrolled; weights uniform -> s_load) ----
    float t1[15];
#pragma unroll
    for (int o = 0; o < 15; ++o) {
        float acc = be1[o];
#pragma unroll
        for (int k = 0; k < 20; ++k) acc = fmaf(We1[o * 20 + k], emb[k], acc);
        t1[o] = fmaxf(acc, 0.0f);
    }
    float t2[10];
#pragma unroll
    for (int o = 0; o < 10; ++o) {
        float acc = be2[o];
#pragma unroll
        for (int k = 0; k < 15; ++k) acc = fmaf(We2[o * 15 + k], t1[k], acc);
        t2[o] = fmaxf(acc, 0.0f);
    }
    float enc[5];
#pragma unroll
    for (int o = 0; o < 5; ++o) {
        float acc = be3[o];
#pragma unroll
        for (int k = 0; k < 10; ++k) acc = fmaf(We3[o * 10 + k], t2[k], acc);
        enc[o] = acc;                       // no relu on encoded
    }
    float t3[10];
#pragma unroll
    for (int o = 0; o < 10; ++o) {
        float acc = bd1[o];
#pragma unroll
        for (int k = 0; k < 5; ++k) acc = fmaf(Wd1[o * 5 + k], enc[k], acc);
        t3[o] = fmaxf(acc, 0.0f);
    }
    float t4[15];
#pragma unroll
    for (int o = 0; o < 15; ++o) {
        float acc = bd2[o];
#pragma unroll
        for (int k = 0; k < 10; ++k) acc = fmaf(Wd2[o * 10 + k], t3[k], acc);
        t4[o] = fmaxf(acc, 0.0f);
    }
    float dec[20];
#pragma unroll
    for (int o = 0; o < 20; ++o) {
        float acc = bd3[o];
#pragma unroll
        for (int k = 0; k < 15; ++k) acc = fmaf(Wd3[o * 15 + k], t4[k], acc);
        dec[o] = acc;                       // no relu on decoded
    }

    // ---- stores ----
    // encoded: 5 floats @ 20B stride -> scalar stores (only 4MB total)
    float* pe = out_enc + (size_t)i * 5;
    pe[0] = enc[0]; pe[1] = enc[1]; pe[2] = enc[2]; pe[3] = enc[3]; pe[4] = enc[4];

    // decoded: 20 floats, 80B stride, 16B aligned -> 5x float4
    float4* pd = (float4*)(out_dec + (size_t)i * 20);
    pd[0] = make_float4(dec[0],  dec[1],  dec[2],  dec[3]);
    pd[1] = make_float4(dec[4],  dec[5],  dec[6],  dec[7]);
    pd[2] = make_float4(dec[8],  dec[9],  dec[10], dec[11]);
    pd[3] = make_float4(dec[12], dec[13], dec[14], dec[15]);
    pd[4] = make_float4(dec[16], dec[17], dec[18], dec[19]);

    // emb: 20 floats, 80B stride, 16B aligned -> 5x float4
    float4* pm = (float4*)(out_emb + (size_t)i * 20);
    pm[0] = make_float4(emb[0],  emb[1],  emb[2],  emb[3]);
    pm[1] = make_float4(emb[4],  emb[5],  emb[6],  emb[7]);
    pm[2] = make_float4(emb[8],  emb[9],  emb[10], emb[11]);
    pm[3] = make_float4(emb[12], emb[13], emb[14], emb[15]);
    pm[4] = make_float4(emb[16], emb[17], emb[18], emb[19]);
}

extern "C" void kernel_launch(void* const* d_in, const int* in_sizes, int n_in,
                              void* d_out, int out_size, void* d_ws, size_t ws_size,
                              hipStream_t stream)
{
    const float* features = (const float*)d_in[0];
    const int*   adj      = (const int*)  d_in[1];
    const float* We1 = (const float*)d_in[2];  const float* be1 = (const float*)d_in[3];
    const float* We2 = (const float*)d_in[4];  const float* be2 = (const float*)d_in[5];
    const float* We3 = (const float*)d_in[6];  const float* be3 = (const float*)d_in[7];
    const float* Wd1 = (const float*)d_in[8];  const float* bd1 = (const float*)d_in[9];
    const float* Wd2 = (const float*)d_in[10]; const float* bd2 = (const float*)d_in[11];
    const float* Wd3 = (const float*)d_in[12]; const float* bd3 = (const float*)d_in[13];

    const int N = in_sizes[0] / NODELEN;

    float* h1pad = (float*)d_ws;               // N * 12 floats = 9.6 MB

    float* out     = (float*)d_out;
    float* out_enc = out;                      // [N][5]
    float* out_dec = out + (size_t)N * 5;      // [N][20]
    float* out_emb = out + (size_t)N * 25;     // [N][20]

    const int threads = 256;
    const int blocks  = (N + threads - 1) / threads;

    hipLaunchKernelGGL(hop1_kernel, dim3(blocks), dim3(threads), 0, stream,
                       features, adj, h1pad, N);
    hipLaunchKernelGGL(hop2_mlp_kernel, dim3(blocks), dim3(threads), 0, stream,
                       features, adj, h1pad,
                       We1, be1, We2, be2, We3, be3,
                       Wd1, bd1, Wd2, bd2, Wd3, bd3,
                       out_enc, out_dec, out_emb, N);
}

// Round 2
// 206.377 us; speedup vs baseline: 2.2904x; 2.2904x over previous
//
#include <hip/hip_runtime.h>

#define NODELEN 10
#define DEG 32

// fp8 tables: one row per node, 10 fp8 bytes used, padded to 16 B so each
// gather is a single global_load_dwordx4 and the whole table (200k x 16 B =
// 3.2 MB) fits in a 4 MiB per-XCD L2 with headroom.

// ---------------------------------------------------------------------------
// fp8 e4m3 (OCP, gfx950) software encode/decode + HW packed decode when
// available. Encode is cold-path (once per node), decode is the hot gather.
// ---------------------------------------------------------------------------
#if defined(__has_builtin)
#if __has_builtin(__builtin_amdgcn_cvt_pk_f32_fp8)
#define USE_HW_FP8_DECODE 1
#endif
#endif

typedef float floatx2 __attribute__((ext_vector_type(2)));

__device__ __forceinline__ float fp8_to_f32_sw(unsigned b) {
    unsigned s = (b & 0x80u) << 24;
    unsigned e = (b >> 3) & 0xFu;
    unsigned m = b & 0x7u;
    // normal: (1 + m/8) * 2^(e-7)  -> f32 exp field = e - 7 + 127 = e + 120
    float fn = __uint_as_float(s | ((e + 120u) << 23) | (m << 20));
    // subnormal (e==0): m * 2^-9
    float fs = __uint_as_float(s | __float_as_uint((float)m * 0.001953125f));
    return e ? fn : fs;
}

// decode a byte-pair (lo 2 bytes or hi 2 bytes of w) and accumulate
__device__ __forceinline__ void dacc(float& a, float& b, unsigned w, int hi) {
#if defined(USE_HW_FP8_DECODE)
    floatx2 f = hi ? __builtin_amdgcn_cvt_pk_f32_fp8(w, true)
                   : __builtin_amdgcn_cvt_pk_f32_fp8(w, false);
    a += f.x; b += f.y;
#else
    unsigned p = hi ? (w >> 16) : w;
    a += fp8_to_f32_sw(p & 0xFFu);
    b += fp8_to_f32_sw((p >> 8) & 0xFFu);
#endif
}

__device__ __forceinline__ unsigned fp8_encode(float f) {
    unsigned u = __float_as_uint(f);
    unsigned s = u >> 31;
    float a = fabsf(f);
    if (a < 0.015625f) {                       // subnormal range: < 2^-6
        int mi = __float2int_rn(a * 512.0f);   // round a / 2^-9, RNE
        // mi in [0,8]; mi==8 encodes as e=1,m=0 which is exactly 2^-6 -> byte=8 is correct
        return (s << 7) | (unsigned)mi;
    }
    int e = (int)((u >> 23) & 0xFFu) - 127;    // e >= -6 here
    unsigned mant = u & 0x7FFFFFu;
    unsigned r = mant + 0x7FFFFu + ((mant >> 20) & 1u);  // RNE to 3 mantissa bits
    mant = r >> 20;                            // 0..8
    if (mant == 8u) { mant = 0u; e += 1; }
    return (s << 7) | ((unsigned)(e + 7) << 3) | mant;
}

__device__ __forceinline__ int4 pack_row_fp8(const float* v) {
    unsigned b[NODELEN];
#pragma unroll
    for (int k = 0; k < NODELEN; ++k) b[k] = fp8_encode(v[k]);
    int4 p;
    p.x = (int)(b[0] | (b[1] << 8) | (b[2] << 16) | (b[3] << 24));
    p.y = (int)(b[4] | (b[5] << 8) | (b[6] << 16) | (b[7] << 24));
    p.z = (int)(b[8] | (b[9] << 8));
    p.w = 0;
    return p;
}

// decode a 16B row (10 fp8) and accumulate into s[10]
__device__ __forceinline__ void row_acc(float* s, int4 p) {
    unsigned w0 = (unsigned)p.x, w1 = (unsigned)p.y, w2 = (unsigned)p.z;
    dacc(s[0], s[1], w0, 0);
    dacc(s[2], s[3], w0, 1);
    dacc(s[4], s[5], w1, 0);
    dacc(s[6], s[7], w1, 1);
    dacc(s[8], s[9], w2, 0);
}

// ---------------------------------------------------------------------------
// Kernel 0: features (fp32, [N][10]) -> fp8 table ([N] x 16B)
// ---------------------------------------------------------------------------
__global__ __launch_bounds__(256) void prep_kernel(
    const float* __restrict__ features,
    int4*        __restrict__ f8feat,
    int N)
{
    int i = blockIdx.x * blockDim.x + threadIdx.x;
    if (i >= N) return;
    const float2* r = (const float2*)(features + (size_t)i * NODELEN);
    float2 a0 = r[0], a1 = r[1], a2 = r[2], a3 = r[3], a4 = r[4];
    float v[NODELEN] = {a0.x, a0.y, a1.x, a1.y, a2.x, a2.y, a3.x, a3.y, a4.x, a4.y};
    f8feat[i] = pack_row_fp8(v);
}

// ---------------------------------------------------------------------------
// Kernel 1: hop-1 mean over fp8 feature table -> fp8 h1 table (col 0 zeroed)
// One thread per node; 32 single-dwordx4 gathers from the L2-resident table.
// ---------------------------------------------------------------------------
__global__ __launch_bounds__(256) void hop1_kernel(
    const int4* __restrict__ f8feat,
    const int*  __restrict__ adj,
    int4*       __restrict__ f8h1,
    int N)
{
    int i = blockIdx.x * blockDim.x + threadIdx.x;
    if (i >= N) return;

    const int4* arow = (const int4*)(adj + (size_t)i * DEG);

    float s[NODELEN];
#pragma unroll
    for (int k = 0; k < NODELEN; ++k) s[k] = 0.0f;

#pragma unroll
    for (int j = 0; j < DEG / 4; ++j) {
        int4 nb = arow[j];
        row_acc(s, f8feat[nb.x]);
        row_acc(s, f8feat[nb.y]);
        row_acc(s, f8feat[nb.z]);
        row_acc(s, f8feat[nb.w]);
    }

    const float inv = 1.0f / (float)DEG;
    float h[NODELEN];
    h[0] = 0.0f;                               // reference zeroes col 0
#pragma unroll
    for (int k = 1; k < NODELEN; ++k) h[k] = s[k] * inv;
    f8h1[i] = pack_row_fp8(h);
}

// ---------------------------------------------------------------------------
// Kernel 2: hop-2 mean over fp8 h1 table + emb build + autoencoder + stores.
// Self-features come from the exact fp32 array (emb[0..9] must be exact-ish).
// ---------------------------------------------------------------------------
__global__ __launch_bounds__(256) void hop2_mlp_kernel(
    const float* __restrict__ features,
    const int*   __restrict__ adj,
    const int4*  __restrict__ f8h1,
    const float* __restrict__ We1, const float* __restrict__ be1,
    const float* __restrict__ We2, const float* __restrict__ be2,
    const float* __restrict__ We3, const float* __restrict__ be3,
    const float* __restrict__ Wd1, const float* __restrict__ bd1,
    const float* __restrict__ Wd2, const float* __restrict__ bd2,
    const float* __restrict__ Wd3, const float* __restrict__ bd3,
    float* __restrict__ out_enc,   // [N][5]
    float* __restrict__ out_dec,   // [N][20]
    float* __restrict__ out_emb,   // [N][20]
    int N)
{
    int i = blockIdx.x * blockDim.x + threadIdx.x;
    if (i >= N) return;

    const int4* arow = (const int4*)(adj + (size_t)i * DEG);

    float s[NODELEN];
#pragma unroll
    for (int k = 0; k < NODELEN; ++k) s[k] = 0.0f;

#pragma unroll
    for (int j = 0; j < DEG / 4; ++j) {
        int4 nb = arow[j];
        row_acc(s, f8h1[nb.x]);
        row_acc(s, f8h1[nb.y]);
        row_acc(s, f8h1[nb.z]);
        row_acc(s, f8h1[nb.w]);
    }

    const float inv = 1.0f / (float)DEG;

    // self features (exact fp32)
    const float2* fr = (const float2*)(features + (size_t)i * NODELEN);
    float2 f0 = fr[0], f1 = fr[1], f2 = fr[2], f3 = fr[3], f4 = fr[4];

    float emb[2 * NODELEN];
    emb[0] = 0.0f;  emb[1] = f0.y;
    emb[2] = f1.x;  emb[3] = f1.y;
    emb[4] = f2.x;  emb[5] = f2.y;
    emb[6] = f3.x;  emb[7] = f3.y;
    emb[8] = f4.x;  emb[9] = f4.y;
    emb[10] = 0.0f;                            // reference zeroes pos NODELEN
#pragma unroll
    for (int k = 1; k < NODELEN; ++k) emb[10 + k] = s[k] * inv;

    // ---- autoencoder (fully unrolled; weights wave-uniform -> s_load) ----
    float t1[15];
#pragma unroll
    for (int o = 0; o < 15; ++o) {
        float acc = be1[o];
#pragma unroll
        for (int k = 0; k < 20; ++k) acc = fmaf(We1[o * 20 + k], emb[k], acc);
        t1[o] = fmaxf(acc, 0.0f);
    }
    float t2[10];
#pragma unroll
    for (int o = 0; o < 10; ++o) {
        float acc = be2[o];
#pragma unroll
        for (int k = 0; k < 15; ++k) acc = fmaf(We2[o * 15 + k], t1[k], acc);
        t2[o] = fmaxf(acc, 0.0f);
    }
    float enc[5];
#pragma unroll
    for (int o = 0; o < 5; ++o) {
        float acc = be3[o];
#pragma unroll
        for (int k = 0; k < 10; ++k) acc = fmaf(We3[o * 10 + k], t2[k], acc);
        enc[o] = acc;
    }
    float t3[10];
#pragma unroll
    for (int o = 0; o < 10; ++o) {
        float acc = bd1[o];
#pragma unroll
        for (int k = 0; k < 5; ++k) acc = fmaf(Wd1[o * 5 + k], enc[k], acc);
        t3[o] = fmaxf(acc, 0.0f);
    }
    float t4[15];
#pragma unroll
    for (int o = 0; o < 15; ++o) {
        float acc = bd2[o];
#pragma unroll
        for (int k = 0; k < 10; ++k) acc = fmaf(Wd2[o * 10 + k], t3[k], acc);
        t4[o] = fmaxf(acc, 0.0f);
    }
    float dec[20];
#pragma unroll
    for (int o = 0; o < 20; ++o) {
        float acc = bd3[o];
#pragma unroll
        for (int k = 0; k < 15; ++k) acc = fmaf(Wd3[o * 15 + k], t4[k], acc);
        dec[o] = acc;
    }

    // ---- stores ----
    float* pe = out_enc + (size_t)i * 5;
    pe[0] = enc[0]; pe[1] = enc[1]; pe[2] = enc[2]; pe[3] = enc[3]; pe[4] = enc[4];

    float4* pd = (float4*)(out_dec + (size_t)i * 20);
    pd[0] = make_float4(dec[0],  dec[1],  dec[2],  dec[3]);
    pd[1] = make_float4(dec[4],  dec[5],  dec[6],  dec[7]);
    pd[2] = make_float4(dec[8],  dec[9],  dec[10], dec[11]);
    pd[3] = make_float4(dec[12], dec[13], dec[14], dec[15]);
    pd[4] = make_float4(dec[16], dec[17], dec[18], dec[19]);

    float4* pm = (float4*)(out_emb + (size_t)i * 20);
    pm[0] = make_float4(emb[0],  emb[1],  emb[2],  emb[3]);
    pm[1] = make_float4(emb[4],  emb[5],  emb[6],  emb[7]);
    pm[2] = make_float4(emb[8],  emb[9],  emb[10], emb[11]);
    pm[3] = make_float4(emb[12], emb[13], emb[14], emb[15]);
    pm[4] = make_float4(emb[16], emb[17], emb[18], emb[19]);
}

extern "C" void kernel_launch(void* const* d_in, const int* in_sizes, int n_in,
                              void* d_out, int out_size, void* d_ws, size_t ws_size,
                              hipStream_t stream)
{
    const float* features = (const float*)d_in[0];
    const int*   adj      = (const int*)  d_in[1];
    const float* We1 = (const float*)d_in[2];  const float* be1 = (const float*)d_in[3];
    const float* We2 = (const float*)d_in[4];  const float* be2 = (const float*)d_in[5];
    const float* We3 = (const float*)d_in[6];  const float* be3 = (const float*)d_in[7];
    const float* Wd1 = (const float*)d_in[8];  const float* bd1 = (const float*)d_in[9];
    const float* Wd2 = (const float*)d_in[10]; const float* bd2 = (const float*)d_in[11];
    const float* Wd3 = (const float*)d_in[12]; const float* bd3 = (const float*)d_in[13];

    const int N = in_sizes[0] / NODELEN;

    int4* f8feat = (int4*)d_ws;                          // N * 16 B = 3.2 MB
    int4* f8h1   = (int4*)((char*)d_ws + (size_t)N * 16); // N * 16 B = 3.2 MB

    float* out     = (float*)d_out;
    float* out_enc = out;                      // [N][5]
    float* out_dec = out + (size_t)N * 5;      // [N][20]
    float* out_emb = out + (size_t)N * 25;     // [N][20]

    const int threads = 256;
    const int blocks  = (N + threads - 1) / threads;

    hipLaunchKernelGGL(prep_kernel, dim3(blocks), dim3(threads), 0, stream,
                       features, f8feat, N);
    hipLaunchKernelGGL(hop1_kernel, dim3(blocks), dim3(threads), 0, stream,
                       f8feat, adj, f8h1, N);
    hipLaunchKernelGGL(hop2_mlp_kernel, dim3(blocks), dim3(threads), 0, stream,
                       features, adj, f8h1,
                       We1, be1, We2, be2, We3, be3,
                       Wd1, bd1, Wd2, bd2, Wd3, bd3,
                       out_enc, out_dec, out_emb, N);
}

// Round 3
// 181.793 us; speedup vs baseline: 2.6002x; 1.1352x over previous
//
#include <hip/hip_runtime.h>

#define NODELEN 10
#define DEG 32
#define NPB 64          // nodes per block in hop2 (256 threads, 4 lanes/node)

// fp8 tables: one row per node, 10 fp8 bytes used, padded to 16 B so each
// gather is a single global_load_dwordx4; table = 200k x 16 B = 3.2 MB.

#if defined(__has_builtin)
#if __has_builtin(__builtin_amdgcn_cvt_pk_f32_fp8)
#define USE_HW_FP8_DECODE 1
#endif
#endif

typedef float floatx2 __attribute__((ext_vector_type(2)));

__device__ __forceinline__ float fp8_to_f32_sw(unsigned b) {
    unsigned s = (b & 0x80u) << 24;
    unsigned e = (b >> 3) & 0xFu;
    unsigned m = b & 0x7u;
    float fn = __uint_as_float(s | ((e + 120u) << 23) | (m << 20));
    float fs = __uint_as_float(s | __float_as_uint((float)m * 0.001953125f));
    return e ? fn : fs;
}

__device__ __forceinline__ void dacc(float& a, float& b, unsigned w, int hi) {
#if defined(USE_HW_FP8_DECODE)
    floatx2 f = hi ? __builtin_amdgcn_cvt_pk_f32_fp8(w, true)
                   : __builtin_amdgcn_cvt_pk_f32_fp8(w, false);
    a += f.x; b += f.y;
#else
    unsigned p = hi ? (w >> 16) : w;
    a += fp8_to_f32_sw(p & 0xFFu);
    b += fp8_to_f32_sw((p >> 8) & 0xFFu);
#endif
}

__device__ __forceinline__ unsigned fp8_encode(float f) {
    unsigned u = __float_as_uint(f);
    unsigned s = u >> 31;
    float a = fabsf(f);
    if (a < 0.015625f) {
        int mi = __float2int_rn(a * 512.0f);
        return (s << 7) | (unsigned)mi;
    }
    int e = (int)((u >> 23) & 0xFFu) - 127;
    unsigned mant = u & 0x7FFFFFu;
    unsigned r = mant + 0x7FFFFu + ((mant >> 20) & 1u);
    mant = r >> 20;
    if (mant == 8u) { mant = 0u; e += 1; }
    return (s << 7) | ((unsigned)(e + 7) << 3) | mant;
}

__device__ __forceinline__ int4 pack_row_fp8(const float* v) {
    unsigned b[NODELEN];
#pragma unroll
    for (int k = 0; k < NODELEN; ++k) b[k] = fp8_encode(v[k]);
    int4 p;
    p.x = (int)(b[0] | (b[1] << 8) | (b[2] << 16) | (b[3] << 24));
    p.y = (int)(b[4] | (b[5] << 8) | (b[6] << 16) | (b[7] << 24));
    p.z = (int)(b[8] | (b[9] << 8));
    p.w = 0;
    return p;
}

__device__ __forceinline__ void row_acc(float* s, int4 p) {
    unsigned w0 = (unsigned)p.x, w1 = (unsigned)p.y, w2 = (unsigned)p.z;
    dacc(s[0], s[1], w0, 0);
    dacc(s[2], s[3], w0, 1);
    dacc(s[4], s[5], w1, 0);
    dacc(s[6], s[7], w1, 1);
    dacc(s[8], s[9], w2, 0);
}

// ---------------------------------------------------------------------------
// Kernel 0: features (fp32 [N][10]) -> fp8 table ([N] x 16B)
// ---------------------------------------------------------------------------
__global__ __launch_bounds__(256) void prep_kernel(
    const float* __restrict__ features,
    int4*        __restrict__ f8feat,
    int N)
{
    int i = blockIdx.x * blockDim.x + threadIdx.x;
    if (i >= N) return;
    const float2* r = (const float2*)(features + (size_t)i * NODELEN);
    float2 a0 = r[0], a1 = r[1], a2 = r[2], a3 = r[3], a4 = r[4];
    float v[NODELEN] = {a0.x, a0.y, a1.x, a1.y, a2.x, a2.y, a3.x, a3.y, a4.x, a4.y};
    f8feat[i] = pack_row_fp8(v);
}

// ---------------------------------------------------------------------------
// Kernel 1: hop-1 mean. 4 lanes/node: each lane gathers 8 neighbors (all
// loads independent -> one latency window), butterfly-reduce, sub==0 stores.
// Active store lanes 0,4,..,60 write 16 consecutive 16B rows -> full lines.
// ---------------------------------------------------------------------------
__global__ __launch_bounds__(256) void hop1_kernel(
    const int4* __restrict__ f8feat,
    const int*  __restrict__ adj,
    int4*       __restrict__ f8h1,
    int N)
{
    int t = blockIdx.x * blockDim.x + threadIdx.x;
    int i = t >> 2, sub = t & 3;
    if (i >= N) return;                    // whole quads retire together

    const int4* arow = (const int4*)(adj + (size_t)i * DEG + sub * 8);
    int4 n0 = arow[0], n1 = arow[1];

    float s[NODELEN];
#pragma unroll
    for (int k = 0; k < NODELEN; ++k) s[k] = 0.0f;
    row_acc(s, f8feat[n0.x]);
    row_acc(s, f8feat[n0.y]);
    row_acc(s, f8feat[n0.z]);
    row_acc(s, f8feat[n0.w]);
    row_acc(s, f8feat[n1.x]);
    row_acc(s, f8feat[n1.y]);
    row_acc(s, f8feat[n1.z]);
    row_acc(s, f8feat[n1.w]);

#pragma unroll
    for (int k = 0; k < NODELEN; ++k) {
        s[k] += __shfl_xor(s[k], 1);
        s[k] += __shfl_xor(s[k], 2);
    }

    if (sub == 0) {
        const float inv = 1.0f / (float)DEG;
        float h[NODELEN];
        h[0] = 0.0f;
#pragma unroll
        for (int k = 1; k < NODELEN; ++k) h[k] = s[k] * inv;
        f8h1[i] = pack_row_fp8(h);
    }
}

// ---------------------------------------------------------------------------
// Kernel 2: hop-2 + MLP + coalesced stores. 256 threads / 64 nodes per block.
// Phase 1: 4 lanes/node gather+reduce -> LDS; features staged coalesced.
// Phase 2: wave 0 runs the MLP (one node/lane), results -> LDS staging.
// Phase 3: all threads flush staging as contiguous float4 (full-line writes,
//          no read-for-ownership).
// ---------------------------------------------------------------------------
__global__ __launch_bounds__(256) void hop2_mlp_kernel(
    const float* __restrict__ features,
    const int*   __restrict__ adj,
    const int4*  __restrict__ f8h1,
    const float* __restrict__ We1, const float* __restrict__ be1,
    const float* __restrict__ We2, const float* __restrict__ be2,
    const float* __restrict__ We3, const float* __restrict__ be3,
    const float* __restrict__ Wd1, const float* __restrict__ bd1,
    const float* __restrict__ Wd2, const float* __restrict__ bd2,
    const float* __restrict__ Wd3, const float* __restrict__ bd3,
    float* __restrict__ out_enc,   // [N][5]
    float* __restrict__ out_dec,   // [N][20]
    float* __restrict__ out_emb,   // [N][20]
    int N)
{
    __shared__ float  s_agg[NPB][11];        // +1 pad breaks stride-10 conflicts
    __shared__ float4 s_feat4[NPB * 10 / 4]; // 64 rows x 40B, flat
    __shared__ float4 s_enc4[NPB * 5 / 4];   // 80
    __shared__ float4 s_dec4[NPB * 20 / 4];  // 320
    __shared__ float4 s_emb4[NPB * 20 / 4];  // 320

    const int tid  = threadIdx.x;
    const int base = blockIdx.x * NPB;
    const int nl   = tid >> 2, sub = tid & 3;
    const int i    = base + nl;
    const bool full = (base + NPB <= N);

    // stage this block's feature rows coalesced (2560B contiguous)
    if (full) {
        const float4* gf = (const float4*)(features + (size_t)base * NODELEN);
        if (tid < NPB * 10 / 4) s_feat4[tid] = gf[tid];
    } else {
        int cnt = (N - base) * NODELEN;
        for (int k = tid; k < cnt; k += 256)
            ((float*)s_feat4)[k] = features[(size_t)base * NODELEN + k];
    }

    // phase 1: gather
    float s[NODELEN];
#pragma unroll
    for (int k = 0; k < NODELEN; ++k) s[k] = 0.0f;
    if (i < N) {
        const int4* arow = (const int4*)(adj + (size_t)i * DEG + sub * 8);
        int4 n0 = arow[0], n1 = arow[1];
        row_acc(s, f8h1[n0.x]);
        row_acc(s, f8h1[n0.y]);
        row_acc(s, f8h1[n0.z]);
        row_acc(s, f8h1[n0.w]);
        row_acc(s, f8h1[n1.x]);
        row_acc(s, f8h1[n1.y]);
        row_acc(s, f8h1[n1.z]);
        row_acc(s, f8h1[n1.w]);
    }
#pragma unroll
    for (int k = 0; k < NODELEN; ++k) {
        s[k] += __shfl_xor(s[k], 1);
        s[k] += __shfl_xor(s[k], 2);
    }
    if (sub == 0 && i < N) {
#pragma unroll
        for (int k = 0; k < NODELEN; ++k) s_agg[nl][k] = s[k];
    }
    __syncthreads();

    // phase 2: wave 0 does the MLP, one node per lane
    if (tid < NPB) {
        int node = base + tid;
        if (node < N) {
            const float inv = 1.0f / (float)DEG;
            const float* fr = (const float*)s_feat4 + tid * NODELEN;

            float emb[2 * NODELEN];
            emb[0] = 0.0f;
#pragma unroll
            for (int k = 1; k < NODELEN; ++k) emb[k] = fr[k];
            emb[NODELEN] = 0.0f;
#pragma unroll
            for (int k = 1; k < NODELEN; ++k) emb[NODELEN + k] = s_agg[tid][k] * inv;

            float t1[15];
#pragma unroll
            for (int o = 0; o < 15; ++o) {
                float acc = be1[o];
#pragma unroll
                for (int k = 0; k < 20; ++k) acc = fmaf(We1[o * 20 + k], emb[k], acc);
                t1[o] = fmaxf(acc, 0.0f);
            }
            float t2[10];
#pragma unroll
            for (int o = 0; o < 10; ++o) {
                float acc = be2[o];
#pragma unroll
                for (int k = 0; k < 15; ++k) acc = fmaf(We2[o * 15 + k], t1[k], acc);
                t2[o] = fmaxf(acc, 0.0f);
            }
            float enc[5];
#pragma unroll
            for (int o = 0; o < 5; ++o) {
                float acc = be3[o];
#pragma unroll
                for (int k = 0; k < 10; ++k) acc = fmaf(We3[o * 10 + k], t2[k], acc);
                enc[o] = acc;
            }
            float t3[10];
#pragma unroll
            for (int o = 0; o < 10; ++o) {
                float acc = bd1[o];
#pragma unroll
                for (int k = 0; k < 5; ++k) acc = fmaf(Wd1[o * 5 + k], enc[k], acc);
                t3[o] = fmaxf(acc, 0.0f);
            }
            float t4[15];
#pragma unroll
            for (int o = 0; o < 15; ++o) {
                float acc = bd2[o];
#pragma unroll
                for (int k = 0; k < 10; ++k) acc = fmaf(Wd2[o * 10 + k], t3[k], acc);
                t4[o] = fmaxf(acc, 0.0f);
            }
            float dec[20];
#pragma unroll
            for (int o = 0; o < 20; ++o) {
                float acc = bd3[o];
#pragma unroll
                for (int k = 0; k < 15; ++k) acc = fmaf(Wd3[o * 15 + k], t4[k], acc);
                dec[o] = acc;
            }

            float* se = (float*)s_enc4;
#pragma unroll
            for (int k = 0; k < 5; ++k) se[tid * 5 + k] = enc[k];
            float* sd = (float*)s_dec4;
#pragma unroll
            for (int k = 0; k < 20; ++k) sd[tid * 20 + k] = dec[k];
            float* sm = (float*)s_emb4;
#pragma unroll
            for (int k = 0; k < 20; ++k) sm[tid * 20 + k] = emb[k];
        }
    }
    __syncthreads();

    // phase 3: coalesced full-line stores
    if (full) {
        float4* gd = (float4*)(out_dec + (size_t)base * 20);
#pragma unroll
        for (int k = tid; k < NPB * 20 / 4; k += 256) gd[k] = s_dec4[k];
        float4* gm = (float4*)(out_emb + (size_t)base * 20);
#pragma unroll
        for (int k = tid; k < NPB * 20 / 4; k += 256) gm[k] = s_emb4[k];
        float4* ge = (float4*)(out_enc + (size_t)base * 5);
        if (tid < NPB * 5 / 4) ge[tid] = s_enc4[tid];
    } else {
        int cnt = N - base;
        for (int k = tid; k < cnt * 20; k += 256)
            out_dec[(size_t)base * 20 + k] = ((float*)s_dec4)[k];
        for (int k = tid; k < cnt * 20; k += 256)
            out_emb[(size_t)base * 20 + k] = ((float*)s_emb4)[k];
        for (int k = tid; k < cnt * 5; k += 256)
            out_enc[(size_t)base * 5 + k] = ((float*)s_enc4)[k];
    }
}

extern "C" void kernel_launch(void* const* d_in, const int* in_sizes, int n_in,
                              void* d_out, int out_size, void* d_ws, size_t ws_size,
                              hipStream_t stream)
{
    const float* features = (const float*)d_in[0];
    const int*   adj      = (const int*)  d_in[1];
    const float* We1 = (const float*)d_in[2];  const float* be1 = (const float*)d_in[3];
    const float* We2 = (const float*)d_in[4];  const float* be2 = (const float*)d_in[5];
    const float* We3 = (const float*)d_in[6];  const float* be3 = (const float*)d_in[7];
    const float* Wd1 = (const float*)d_in[8];  const float* bd1 = (const float*)d_in[9];
    const float* Wd2 = (const float*)d_in[10]; const float* bd2 = (const float*)d_in[11];
    const float* Wd3 = (const float*)d_in[12]; const float* bd3 = (const float*)d_in[13];

    const int N = in_sizes[0] / NODELEN;

    int4* f8feat = (int4*)d_ws;                           // N * 16 B = 3.2 MB
    int4* f8h1   = (int4*)((char*)d_ws + (size_t)N * 16); // N * 16 B = 3.2 MB

    float* out     = (float*)d_out;
    float* out_enc = out;                      // [N][5]
    float* out_dec = out + (size_t)N * 5;      // [N][20]
    float* out_emb = out + (size_t)N * 25;     // [N][20]

    const int threads = 256;

    hipLaunchKernelGGL(prep_kernel, dim3((N + 255) / 256), dim3(threads), 0, stream,
                       features, f8feat, N);
    hipLaunchKernelGGL(hop1_kernel, dim3((4 * N + 255) / 256), dim3(threads), 0, stream,
                       f8feat, adj, f8h1, N);
    hipLaunchKernelGGL(hop2_mlp_kernel, dim3((N + NPB - 1) / NPB), dim3(threads), 0, stream,
                       features, adj, f8h1,
                       We1, be1, We2, be2, We3, be3,
                       Wd1, bd1, Wd2, bd2, Wd3, bd3,
                       out_enc, out_dec, out_emb, N);
}

// Round 4
// 180.776 us; speedup vs baseline: 2.6148x; 1.0056x over previous
//
#include <hip/hip_runtime.h>

#define NODELEN 10
#define DEG 32
#define NPB 64          // nodes per block in hop2 (256 threads, 4 lanes/node)

// fp8 tables: one row per node, 10 fp8 bytes used, padded to 16 B so each
// gather is a single global_load_dwordx4; table = 200k x 16 B = 3.2 MB,
// fits per-XCD 4 MiB L2 -> gathers are L2 hits after warm-up.

#if defined(__has_builtin)
#if __has_builtin(__builtin_amdgcn_cvt_pk_f32_fp8)
#define USE_HW_FP8_DECODE 1
#endif
#endif

typedef float floatx2 __attribute__((ext_vector_type(2)));

__device__ __forceinline__ float fp8_to_f32_sw(unsigned b) {
    unsigned s = (b & 0x80u) << 24;
    unsigned e = (b >> 3) & 0xFu;
    unsigned m = b & 0x7u;
    float fn = __uint_as_float(s | ((e + 120u) << 23) | (m << 20));
    float fs = __uint_as_float(s | __float_as_uint((float)m * 0.001953125f));
    return e ? fn : fs;
}

__device__ __forceinline__ void dacc(float& a, float& b, unsigned w, int hi) {
#if defined(USE_HW_FP8_DECODE)
    floatx2 f = hi ? __builtin_amdgcn_cvt_pk_f32_fp8(w, true)
                   : __builtin_amdgcn_cvt_pk_f32_fp8(w, false);
    a += f.x; b += f.y;
#else
    unsigned p = hi ? (w >> 16) : w;
    a += fp8_to_f32_sw(p & 0xFFu);
    b += fp8_to_f32_sw((p >> 8) & 0xFFu);
#endif
}

__device__ __forceinline__ unsigned fp8_encode(float f) {
    unsigned u = __float_as_uint(f);
    unsigned s = u >> 31;
    float a = fabsf(f);
    if (a < 0.015625f) {
        int mi = __float2int_rn(a * 512.0f);
        return (s << 7) | (unsigned)mi;
    }
    int e = (int)((u >> 23) & 0xFFu) - 127;
    unsigned mant = u & 0x7FFFFFu;
    unsigned r = mant + 0x7FFFFu + ((mant >> 20) & 1u);
    mant = r >> 20;
    if (mant == 8u) { mant = 0u; e += 1; }
    return (s << 7) | ((unsigned)(e + 7) << 3) | mant;
}

__device__ __forceinline__ int4 pack_row_fp8(const float* v) {
    unsigned b[NODELEN];
#pragma unroll
    for (int k = 0; k < NODELEN; ++k) b[k] = fp8_encode(v[k]);
    int4 p;
    p.x = (int)(b[0] | (b[1] << 8) | (b[2] << 16) | (b[3] << 24));
    p.y = (int)(b[4] | (b[5] << 8) | (b[6] << 16) | (b[7] << 24));
    p.z = (int)(b[8] | (b[9] << 8));
    p.w = 0;
    return p;
}

__device__ __forceinline__ void row_acc(float* s, int4 p) {
    unsigned w0 = (unsigned)p.x, w1 = (unsigned)p.y, w2 = (unsigned)p.z;
    dacc(s[0], s[1], w0, 0);
    dacc(s[2], s[3], w0, 1);
    dacc(s[4], s[5], w1, 0);
    dacc(s[6], s[7], w1, 1);
    dacc(s[8], s[9], w2, 0);
}

// gather 8 rows (all loads issued before any decode -> one latency window),
// then decode+accumulate. Named temps force the loads to stay in flight.
__device__ __forceinline__ void gather8_acc(float* s, const int4* __restrict__ tab,
                                            int4 n0, int4 n1) {
    int4 r0 = tab[n0.x];
    int4 r1 = tab[n0.y];
    int4 r2 = tab[n0.z];
    int4 r3 = tab[n0.w];
    int4 r4 = tab[n1.x];
    int4 r5 = tab[n1.y];
    int4 r6 = tab[n1.z];
    int4 r7 = tab[n1.w];
    row_acc(s, r0);
    row_acc(s, r1);
    row_acc(s, r2);
    row_acc(s, r3);
    row_acc(s, r4);
    row_acc(s, r5);
    row_acc(s, r6);
    row_acc(s, r7);
}

// ---------------------------------------------------------------------------
// Kernel 0: features (fp32 [N][10]) -> fp8 table ([N] x 16B)
// ---------------------------------------------------------------------------
__global__ __launch_bounds__(256) void prep_kernel(
    const float* __restrict__ features,
    int4*        __restrict__ f8feat,
    int N)
{
    int i = blockIdx.x * blockDim.x + threadIdx.x;
    if (i >= N) return;
    const float2* r = (const float2*)(features + (size_t)i * NODELEN);
    float2 a0 = r[0], a1 = r[1], a2 = r[2], a3 = r[3], a4 = r[4];
    float v[NODELEN] = {a0.x, a0.y, a1.x, a1.y, a2.x, a2.y, a3.x, a3.y, a4.x, a4.y};
    f8feat[i] = pack_row_fp8(v);
}

// ---------------------------------------------------------------------------
// Kernel 1: hop-1 mean. 4 lanes/node, 8 batched gathers per lane, butterfly
// reduce, sub==0 lanes store 16 consecutive 16B rows per wave (full lines).
// ---------------------------------------------------------------------------
__global__ __launch_bounds__(256) void hop1_kernel(
    const int4* __restrict__ f8feat,
    const int*  __restrict__ adj,
    int4*       __restrict__ f8h1,
    int N)
{
    int t = blockIdx.x * blockDim.x + threadIdx.x;
    int i = t >> 2, sub = t & 3;
    if (i >= N) return;                    // whole quads retire together

    const int4* arow = (const int4*)(adj + (size_t)i * DEG + sub * 8);
    int4 n0 = arow[0], n1 = arow[1];

    float s[NODELEN];
#pragma unroll
    for (int k = 0; k < NODELEN; ++k) s[k] = 0.0f;
    gather8_acc(s, f8feat, n0, n1);

#pragma unroll
    for (int k = 0; k < NODELEN; ++k) {
        s[k] += __shfl_xor(s[k], 1);
        s[k] += __shfl_xor(s[k], 2);
    }

    if (sub == 0) {
        const float inv = 1.0f / (float)DEG;
        float h[NODELEN];
        h[0] = 0.0f;
#pragma unroll
        for (int k = 1; k < NODELEN; ++k) h[k] = s[k] * inv;
        f8h1[i] = pack_row_fp8(h);
    }
}

// ---------------------------------------------------------------------------
// Kernel 2: hop-2 + MLP + coalesced stores. 256 threads / 64 nodes per block.
// ---------------------------------------------------------------------------
__global__ __launch_bounds__(256) void hop2_mlp_kernel(
    const float* __restrict__ features,
    const int*   __restrict__ adj,
    const int4*  __restrict__ f8h1,
    const float* __restrict__ We1, const float* __restrict__ be1,
    const float* __restrict__ We2, const float* __restrict__ be2,
    const float* __restrict__ We3, const float* __restrict__ be3,
    const float* __restrict__ Wd1, const float* __restrict__ bd1,
    const float* __restrict__ Wd2, const float* __restrict__ bd2,
    const float* __restrict__ Wd3, const float* __restrict__ bd3,
    float* __restrict__ out_enc,   // [N][5]
    float* __restrict__ out_dec,   // [N][20]
    float* __restrict__ out_emb,   // [N][20]
    int N)
{
    __shared__ float  s_agg[NPB][11];        // +1 pad breaks stride-10 conflicts
    __shared__ float4 s_feat4[NPB * 10 / 4]; // 64 rows x 40B, flat
    __shared__ float4 s_enc4[NPB * 5 / 4];   // 80
    __shared__ float4 s_dec4[NPB * 20 / 4];  // 320
    __shared__ float4 s_emb4[NPB * 20 / 4];  // 320

    const int tid  = threadIdx.x;
    const int base = blockIdx.x * NPB;
    const int nl   = tid >> 2, sub = tid & 3;
    const int i    = base + nl;
    const bool full = (base + NPB <= N);

    // stage this block's feature rows coalesced (2560B contiguous)
    if (full) {
        const float4* gf = (const float4*)(features + (size_t)base * NODELEN);
        if (tid < NPB * 10 / 4) s_feat4[tid] = gf[tid];
    } else {
        int cnt = (N - base) * NODELEN;
        for (int k = tid; k < cnt; k += 256)
            ((float*)s_feat4)[k] = features[(size_t)base * NODELEN + k];
    }

    // phase 1: gather (8 loads per lane in one latency window)
    float s[NODELEN];
#pragma unroll
    for (int k = 0; k < NODELEN; ++k) s[k] = 0.0f;
    if (i < N) {
        const int4* arow = (const int4*)(adj + (size_t)i * DEG + sub * 8);
        int4 n0 = arow[0], n1 = arow[1];
        gather8_acc(s, f8h1, n0, n1);
    }
#pragma unroll
    for (int k = 0; k < NODELEN; ++k) {
        s[k] += __shfl_xor(s[k], 1);
        s[k] += __shfl_xor(s[k], 2);
    }
    if (sub == 0 && i < N) {
#pragma unroll
        for (int k = 0; k < NODELEN; ++k) s_agg[nl][k] = s[k];
    }
    __syncthreads();

    // phase 2: wave 0 does the MLP, one node per lane
    if (tid < NPB) {
        int node = base + tid;
        if (node < N) {
            const float inv = 1.0f / (float)DEG;
            const float* fr = (const float*)s_feat4 + tid * NODELEN;

            float emb[2 * NODELEN];
            emb[0] = 0.0f;
#pragma unroll
            for (int k = 1; k < NODELEN; ++k) emb[k] = fr[k];
            emb[NODELEN] = 0.0f;
#pragma unroll
            for (int k = 1; k < NODELEN; ++k) emb[NODELEN + k] = s_agg[tid][k] * inv;

            float t1[15];
#pragma unroll
            for (int o = 0; o < 15; ++o) {
                float acc = be1[o];
#pragma unroll
                for (int k = 0; k < 20; ++k) acc = fmaf(We1[o * 20 + k], emb[k], acc);
                t1[o] = fmaxf(acc, 0.0f);
            }
            float t2[10];
#pragma unroll
            for (int o = 0; o < 10; ++o) {
                float acc = be2[o];
#pragma unroll
                for (int k = 0; k < 15; ++k) acc = fmaf(We2[o * 15 + k], t1[k], acc);
                t2[o] = fmaxf(acc, 0.0f);
            }
            float enc[5];
#pragma unroll
            for (int o = 0; o < 5; ++o) {
                float acc = be3[o];
#pragma unroll
                for (int k = 0; k < 10; ++k) acc = fmaf(We3[o * 10 + k], t2[k], acc);
                enc[o] = acc;
            }
            float t3[10];
#pragma unroll
            for (int o = 0; o < 10; ++o) {
                float acc = bd1[o];
#pragma unroll
                for (int k = 0; k < 5; ++k) acc = fmaf(Wd1[o * 5 + k], enc[k], acc);
                t3[o] = fmaxf(acc, 0.0f);
            }
            float t4[15];
#pragma unroll
            for (int o = 0; o < 15; ++o) {
                float acc = bd2[o];
#pragma unroll
                for (int k = 0; k < 10; ++k) acc = fmaf(Wd2[o * 10 + k], t3[k], acc);
                t4[o] = fmaxf(acc, 0.0f);
            }
            float dec[20];
#pragma unroll
            for (int o = 0; o < 20; ++o) {
                float acc = bd3[o];
#pragma unroll
                for (int k = 0; k < 15; ++k) acc = fmaf(Wd3[o * 15 + k], t4[k], acc);
                dec[o] = acc;
            }

            float* se = (float*)s_enc4;
#pragma unroll
            for (int k = 0; k < 5; ++k) se[tid * 5 + k] = enc[k];
            float* sd = (float*)s_dec4;
#pragma unroll
            for (int k = 0; k < 20; ++k) sd[tid * 20 + k] = dec[k];
            float* sm = (float*)s_emb4;
#pragma unroll
            for (int k = 0; k < 20; ++k) sm[tid * 20 + k] = emb[k];
        }
    }
    __syncthreads();

    // phase 3: coalesced full-line stores
    if (full) {
        float4* gd = (float4*)(out_dec + (size_t)base * 20);
#pragma unroll
        for (int k = tid; k < NPB * 20 / 4; k += 256) gd[k] = s_dec4[k];
        float4* gm = (float4*)(out_emb + (size_t)base * 20);
#pragma unroll
        for (int k = tid; k < NPB * 20 / 4; k += 256) gm[k] = s_emb4[k];
        float4* ge = (float4*)(out_enc + (size_t)base * 5);
        if (tid < NPB * 5 / 4) ge[tid] = s_enc4[tid];
    } else {
        int cnt = N - base;
        for (int k = tid; k < cnt * 20; k += 256)
            out_dec[(size_t)base * 20 + k] = ((float*)s_dec4)[k];
        for (int k = tid; k < cnt * 20; k += 256)
            out_emb[(size_t)base * 20 + k] = ((float*)s_emb4)[k];
        for (int k = tid; k < cnt * 5; k += 256)
            out_enc[(size_t)base * 5 + k] = ((float*)s_enc4)[k];
    }
}

extern "C" void kernel_launch(void* const* d_in, const int* in_sizes, int n_in,
                              void* d_out, int out_size, void* d_ws, size_t ws_size,
                              hipStream_t stream)
{
    const float* features = (const float*)d_in[0];
    const int*   adj      = (const int*)  d_in[1];
    const float* We1 = (const float*)d_in[2];  const float* be1 = (const float*)d_in[3];
    const float* We2 = (const float*)d_in[4];  const float* be2 = (const float*)d_in[5];
    const float* We3 = (const float*)d_in[6];  const float* be3 = (const float*)d_in[7];
    const float* Wd1 = (const float*)d_in[8];  const float* bd1 = (const float*)d_in[9];
    const float* Wd2 = (const float*)d_in[10]; const float* bd2 = (const float*)d_in[11];
    const float* Wd3 = (const float*)d_in[12]; const float* bd3 = (const float*)d_in[13];

    const int N = in_sizes[0] / NODELEN;

    int4* f8feat = (int4*)d_ws;                           // N * 16 B = 3.2 MB
    int4* f8h1   = (int4*)((char*)d_ws + (size_t)N * 16); // N * 16 B = 3.2 MB

    float* out     = (float*)d_out;
    float* out_enc = out;                      // [N][5]
    float* out_dec = out + (size_t)N * 5;      // [N][20]
    float* out_emb = out + (size_t)N * 25;     // [N][20]

    const int threads = 256;

    hipLaunchKernelGGL(prep_kernel, dim3((N + 255) / 256), dim3(threads), 0, stream,
                       features, f8feat, N);
    hipLaunchKernelGGL(hop1_kernel, dim3((4 * N + 255) / 256), dim3(threads), 0, stream,
                       f8feat, adj, f8h1, N);
    hipLaunchKernelGGL(hop2_mlp_kernel, dim3((N + NPB - 1) / NPB), dim3(threads), 0, stream,
                       features, adj, f8h1,
                       We1, be1, We2, be2, We3, be3,
                       Wd1, bd1, Wd2, bd2, Wd3, bd3,
                       out_enc, out_dec, out_emb, N);
}